// Round 1
// baseline (340.810 us; speedup 1.0000x reference)
//
#include <hip/hip_runtime.h>

#define DEVINL __device__ __forceinline__

typedef unsigned short u16;
typedef __attribute__((ext_vector_type(8))) short s16x8;
typedef __attribute__((ext_vector_type(4))) float f32x4;

static constexpr int Bb = 4, Tt = 2048, Cc = 1024, Hh = 16, Dd = 64;
static constexpr int Mm = Bb * Tt;  // 8192
static constexpr int KK = Cc;       // 1024

DEVINL float bf2f(u16 u) { return __uint_as_float(((unsigned)u) << 16); }
DEVINL u16 f2bf(float f) {
  unsigned b = __float_as_uint(f);
  b += 0x7fff + ((b >> 16) & 1);  // RNE
  return (u16)(b >> 16);
}

// ---------------- f32 -> bf16 convert (x4 vectorized) ----------------
__global__ void cvt_bf16(const float* __restrict__ src, u16* __restrict__ dst, int n4) {
  int i = blockIdx.x * blockDim.x + threadIdx.x;
  int st = gridDim.x * blockDim.x;
  for (int g = i; g < n4; g += st) {
    float4 v = ((const float4*)src)[g];
    uint2 o;
    o.x = (unsigned)f2bf(v.x) | ((unsigned)f2bf(v.y) << 16);
    o.y = (unsigned)f2bf(v.z) | ((unsigned)f2bf(v.w) << 16);
    ((uint2*)dst)[g] = o;
  }
}

// ---------------- RoPE in-place on q,k (bf16, (B,H,T,D)) ----------------
__global__ void rope_kernel(u16* __restrict__ q, u16* __restrict__ k,
                            const float* __restrict__ cache) {
  const int total = Bb * Hh * Tt * 8;  // groups of 8 elems
  int i = blockIdx.x * blockDim.x + threadIdx.x;
  int st = gridDim.x * blockDim.x;
  for (int g = i; g < total; g += st) {
    int off = g * 8;
    int t = (off >> 6) & (Tt - 1);
    int d0 = off & 63;
    const float* cp = cache + t * 64 + d0;  // (T, 32, 2) interleaved cos/sin
    float4 c0 = *(const float4*)cp;
    float4 c1 = *(const float4*)(cp + 4);
    float cs[8] = {c0.x, c0.y, c0.z, c0.w, c1.x, c1.y, c1.z, c1.w};
    s16x8 qv = *(s16x8*)(q + off);
    s16x8 kv = *(s16x8*)(k + off);
    s16x8 qo, ko;
#pragma unroll
    for (int p = 0; p < 4; ++p) {
      float c = cs[2 * p], s = cs[2 * p + 1];
      float a = bf2f((u16)qv[2 * p]), b = bf2f((u16)qv[2 * p + 1]);
      qo[2 * p] = (short)f2bf(a * c - b * s);
      qo[2 * p + 1] = (short)f2bf(a * s + b * c);
      a = bf2f((u16)kv[2 * p]); b = bf2f((u16)kv[2 * p + 1]);
      ko[2 * p] = (short)f2bf(a * c - b * s);
      ko[2 * p + 1] = (short)f2bf(a * s + b * c);
    }
    *(s16x8*)(q + off) = qo;
    *(s16x8*)(k + off) = ko;
  }
}

// ---------------- bf16 GEMM: out = A(8192x1024) @ W^T + bias ----------------
// MODE 0: write bf16 into (B,H,T,D) layout, z selects {q,k,v}
// MODE 1: write f32 flat (M x C)
struct GemmArgs {
  const u16* A;
  const u16* W[3];
  const float* bias[3];
  void* out[3];
};

template <int MODE>
__global__ __launch_bounds__(256) void gemm_bt(GemmArgs args) {
  __shared__ __align__(16) u16 As[128 * 64];
  __shared__ __align__(16) u16 Bs[128 * 64];
  const int z = blockIdx.z;
  const u16* __restrict__ A = args.A;
  const u16* __restrict__ Wt = args.W[z];
  const float* __restrict__ bias = args.bias[z];
  const int tid = threadIdx.x, w = tid >> 6, l = tid & 63;
  const int lr = l & 15, lg = l >> 4;
  const int m0 = blockIdx.x * 128, n0 = blockIdx.y * 128;
  const int wr = w >> 1, wc = w & 1;
  f32x4 zero = {0.f, 0.f, 0.f, 0.f};
  f32x4 acc[4][4];
#pragma unroll
  for (int i = 0; i < 4; ++i)
#pragma unroll
    for (int j = 0; j < 4; ++j) acc[i][j] = zero;

  const int srow = l >> 3;        // 0..7
  const int scol = (l & 7) * 8;   // 0..56
  s16x8 av[4], bv[4];
  auto loadAB = [&](int k0) {
#pragma unroll
    for (int i = 0; i < 4; ++i) {
      int row = i * 32 + w * 8 + srow;
      av[i] = *(const s16x8*)(A + (size_t)(m0 + row) * KK + k0 + scol);
      bv[i] = *(const s16x8*)(Wt + (size_t)(n0 + row) * KK + k0 + scol);
    }
  };
  loadAB(0);
  for (int k0 = 0; k0 < KK; k0 += 64) {
    __syncthreads();  // prior compute done reading LDS
#pragma unroll
    for (int i = 0; i < 4; ++i) {
      int row = i * 32 + w * 8 + srow;
      int sc = scol ^ ((row & 7) << 3);  // XOR swizzle, both-sides
      *(s16x8*)&As[row * 64 + sc] = av[i];
      *(s16x8*)&Bs[row * 64 + sc] = bv[i];
    }
    __syncthreads();
    if (k0 + 64 < KK) loadAB(k0 + 64);  // prefetch next tile under MFMA
#pragma unroll
    for (int kk = 0; kk < 2; ++kk) {
      s16x8 af[4], bfr[4];
#pragma unroll
      for (int i = 0; i < 4; ++i)
        af[i] = *(const s16x8*)&As[(wr * 64 + i * 16 + lr) * 64 +
                                   ((kk * 32 + lg * 8) ^ ((lr & 7) << 3))];
#pragma unroll
      for (int j = 0; j < 4; ++j)
        bfr[j] = *(const s16x8*)&Bs[(wc * 64 + j * 16 + lr) * 64 +
                                    ((kk * 32 + lg * 8) ^ ((lr & 7) << 3))];
#pragma unroll
      for (int i = 0; i < 4; ++i)
#pragma unroll
        for (int j = 0; j < 4; ++j)
          acc[i][j] = __builtin_amdgcn_mfma_f32_16x16x32_bf16(af[i], bfr[j], acc[i][j], 0, 0, 0);
    }
  }
  // epilogue: C/D layout col=lane&15, row=(lane>>4)*4+r
  if (MODE == 0) {
    u16* O = (u16*)args.out[z];
#pragma unroll
    for (int j = 0; j < 4; ++j) {
      int ncol = n0 + wc * 64 + j * 16 + lr;
      float bj = bias[ncol];
      int hh = ncol >> 6, dd = ncol & 63;
#pragma unroll
      for (int i = 0; i < 4; ++i) {
#pragma unroll
        for (int r = 0; r < 4; ++r) {
          int mrow = m0 + wr * 64 + i * 16 + lg * 4 + r;
          int bb2 = mrow >> 11, tt2 = mrow & (Tt - 1);
          O[(((size_t)bb2 * Hh + hh) * Tt + tt2) * Dd + dd] = f2bf(acc[i][j][r] + bj);
        }
      }
    }
  } else {
    float* O = (float*)args.out[0];
#pragma unroll
    for (int j = 0; j < 4; ++j) {
      int ncol = n0 + wc * 64 + j * 16 + lr;
      float bj = bias[ncol];
#pragma unroll
      for (int i = 0; i < 4; ++i) {
#pragma unroll
        for (int r = 0; r < 4; ++r) {
          int mrow = m0 + wr * 64 + i * 16 + lg * 4 + r;
          O[(size_t)mrow * Cc + ncol] = acc[i][j][r] + bj;
        }
      }
    }
  }
}

// ---------------- causal flash attention ----------------
// grid (T/64, B*H), 256 threads; wave w owns 16 q-rows.
__global__ __launch_bounds__(256) void attn_kernel(const u16* __restrict__ Q,
                                                   const u16* __restrict__ K,
                                                   const u16* __restrict__ V,
                                                   u16* __restrict__ Out) {
  __shared__ __align__(16) u16 Ks[64 * 64];        // [key][d] swizzled
  __shared__ __align__(16) u16 VTs[64 * 64];       // [d][key] swizzled
  __shared__ __align__(16) u16 Ps[4 * 16 * 64];    // per-wave [q][key] swizzled
  const int tid = threadIdx.x, w = tid >> 6, l = tid & 63;
  const int lr = l & 15, lg = l >> 4;
  const int bh = blockIdx.y;
  const int qb0 = blockIdx.x * 64;
  const size_t base = (size_t)bh * Tt * Dd;
  const u16* Qp = Q + base;
  const u16* Kp = K + base;
  const u16* Vp = V + base;
  const int qrow = qb0 + w * 16 + lr;
  s16x8 qf[2];
  qf[0] = *(const s16x8*)(Qp + (size_t)qrow * 64 + lg * 8);
  qf[1] = *(const s16x8*)(Qp + (size_t)qrow * 64 + 32 + lg * 8);
  f32x4 zero = {0.f, 0.f, 0.f, 0.f};
  f32x4 o[4] = {zero, zero, zero, zero};
  float mrow[4] = {-1e30f, -1e30f, -1e30f, -1e30f};
  float lsum[4] = {0.f, 0.f, 0.f, 0.f};
  const int ktiles = blockIdx.x + 1;
  s16x8 kv[2], vv[2];
  auto loadKV = [&](int kk0) {
#pragma unroll
    for (int i = 0; i < 2; ++i) {
      int d0 = (w + i * 4) * 8;
      kv[i] = *(const s16x8*)(Kp + (size_t)(kk0 + l) * 64 + d0);
      vv[i] = *(const s16x8*)(Vp + (size_t)(kk0 + l) * 64 + d0);
    }
  };
  loadKV(0);
  for (int kt = 0; kt < ktiles; ++kt) {
    const int kk0 = kt * 64;
    __syncthreads();  // prior iter done reading Ks/VTs
#pragma unroll
    for (int i = 0; i < 2; ++i) {
      int d0 = (w + i * 4) * 8;
      *(s16x8*)&Ks[l * 64 + (d0 ^ ((l & 7) << 3))] = kv[i];
#pragma unroll
      for (int j = 0; j < 8; ++j)
        VTs[(d0 + j) * 64 + (l ^ (j << 3))] = (u16)vv[i][j];  // (d0+j)&7 == j
    }
    __syncthreads();
    if (kt + 1 < ktiles) loadKV(kk0 + 64);  // prefetch under compute
    // ---- QK^T: S[16q x 64key] in 4 col-frags
    float pv[4][4];
#pragma unroll
    for (int cf = 0; cf < 4; ++cf) {
      f32x4 s = zero;
#pragma unroll
      for (int kf = 0; kf < 2; ++kf) {
        s16x8 kb = *(const s16x8*)&Ks[(cf * 16 + lr) * 64 +
                                      ((kf * 32 + lg * 8) ^ ((lr & 7) << 3))];
        s = __builtin_amdgcn_mfma_f32_16x16x32_bf16(qf[kf], kb, s, 0, 0, 0);
      }
      int key = kk0 + cf * 16 + lr;
#pragma unroll
      for (int r = 0; r < 4; ++r) {
        int qg = qb0 + w * 16 + lg * 4 + r;
        pv[cf][r] = (key <= qg) ? s[r] * 0.125f : -1e10f;
      }
    }
    // ---- online softmax (rows live across the 16-lane groups)
#pragma unroll
    for (int r = 0; r < 4; ++r) {
      float tm = fmaxf(fmaxf(pv[0][r], pv[1][r]), fmaxf(pv[2][r], pv[3][r]));
#pragma unroll
      for (int off = 8; off > 0; off >>= 1) tm = fmaxf(tm, __shfl_xor(tm, off, 16));
      float mnew = fmaxf(mrow[r], tm);
      float fsc = __expf(mrow[r] - mnew);
      float psum = 0.f;
#pragma unroll
      for (int cf = 0; cf < 4; ++cf) {
        float p = __expf(pv[cf][r] - mnew);
        pv[cf][r] = p;
        psum += p;
      }
#pragma unroll
      for (int off = 8; off > 0; off >>= 1) psum += __shfl_xor(psum, off, 16);
      lsum[r] = lsum[r] * fsc + psum;
      mrow[r] = mnew;
      o[0][r] *= fsc; o[1][r] *= fsc; o[2][r] *= fsc; o[3][r] *= fsc;
    }
    // ---- P -> per-wave LDS (C-frag layout -> A-frag layout)
#pragma unroll
    for (int cf = 0; cf < 4; ++cf) {
#pragma unroll
      for (int r = 0; r < 4; ++r) {
        int row = lg * 4 + r;
        Ps[w * 1024 + row * 64 + ((cf * 16 + lr) ^ ((row & 7) << 3))] = f2bf(pv[cf][r]);
      }
    }
    // ---- PV: O += P(16x64) @ V(64x64)
#pragma unroll
    for (int kk = 0; kk < 2; ++kk) {
      s16x8 pa = *(const s16x8*)&Ps[w * 1024 + lr * 64 +
                                    ((kk * 32 + lg * 8) ^ ((lr & 7) << 3))];
#pragma unroll
      for (int jf = 0; jf < 4; ++jf) {
        s16x8 vb = *(const s16x8*)&VTs[(jf * 16 + lr) * 64 +
                                       ((kk * 32 + lg * 8) ^ ((lr & 7) << 3))];
        o[jf] = __builtin_amdgcn_mfma_f32_16x16x32_bf16(pa, vb, o[jf], 0, 0, 0);
      }
    }
  }
  // ---- epilogue: write (B,T,H*D) bf16
  const int bb2 = bh >> 4, hh = bh & 15;
#pragma unroll
  for (int jf = 0; jf < 4; ++jf) {
#pragma unroll
    for (int r = 0; r < 4; ++r) {
      int tq = qb0 + w * 16 + lg * 4 + r;
      float val = o[jf][r] / lsum[r];
      Out[((size_t)(bb2 * Tt + tq)) * Cc + hh * 64 + jf * 16 + lr] = f2bf(val);
    }
  }
}

extern "C" void kernel_launch(void* const* d_in, const int* in_sizes, int n_in,
                              void* d_out, int out_size, void* d_ws, size_t ws_size,
                              hipStream_t stream) {
  (void)in_sizes; (void)n_in; (void)out_size; (void)ws_size;
  const float* x = (const float*)d_in[0];
  const float* Wq = (const float*)d_in[1];
  const float* bq = (const float*)d_in[2];
  const float* Wk = (const float*)d_in[3];
  const float* bk = (const float*)d_in[4];
  const float* Wv = (const float*)d_in[5];
  const float* bv = (const float*)d_in[6];
  const float* Wp = (const float*)d_in[7];
  const float* bp = (const float*)d_in[8];
  const float* rope = (const float*)d_in[9];

  char* ws = (char*)d_ws;
  const size_t MB = 1024 * 1024;
  u16* xb  = (u16*)(ws + 0);        // 16 MB: x as bf16 (8192x1024)
  u16* wqb = (u16*)(ws + 16 * MB);  // 2 MB each
  u16* wkb = (u16*)(ws + 18 * MB);
  u16* wvb = (u16*)(ws + 20 * MB);
  u16* wpb = (u16*)(ws + 22 * MB);
  u16* qb  = (u16*)(ws + 24 * MB);  // 16 MB each, (B,H,T,D) bf16
  u16* kb  = (u16*)(ws + 40 * MB);
  u16* vb  = (u16*)(ws + 56 * MB);
  u16* att = (u16*)(ws + 72 * MB);  // 16 MB, (B,T,C) bf16  -> ends 88 MB

  cvt_bf16<<<2048, 256, 0, stream>>>(x, xb, (Mm * Cc) / 4);
  cvt_bf16<<<512, 256, 0, stream>>>(Wq, wqb, (Cc * Cc) / 4);
  cvt_bf16<<<512, 256, 0, stream>>>(Wk, wkb, (Cc * Cc) / 4);
  cvt_bf16<<<512, 256, 0, stream>>>(Wv, wvb, (Cc * Cc) / 4);
  cvt_bf16<<<512, 256, 0, stream>>>(Wp, wpb, (Cc * Cc) / 4);

  GemmArgs ga;
  ga.A = xb;
  ga.W[0] = wqb; ga.W[1] = wkb; ga.W[2] = wvb;
  ga.bias[0] = bq; ga.bias[1] = bk; ga.bias[2] = bv;
  ga.out[0] = qb; ga.out[1] = kb; ga.out[2] = vb;
  gemm_bt<0><<<dim3(Mm / 128, Cc / 128, 3), 256, 0, stream>>>(ga);

  rope_kernel<<<2048, 256, 0, stream>>>(qb, kb, rope);

  attn_kernel<<<dim3(Tt / 64, Bb * Hh), 256, 0, stream>>>(qb, kb, vb, att);

  GemmArgs gp;
  gp.A = att;
  gp.W[0] = wpb; gp.W[1] = wpb; gp.W[2] = wpb;
  gp.bias[0] = bp; gp.bias[1] = bp; gp.bias[2] = bp;
  gp.out[0] = d_out; gp.out[1] = d_out; gp.out[2] = d_out;
  gemm_bt<1><<<dim3(Mm / 128, Cc / 128, 1), 256, 0, stream>>>(gp);
}

// Round 2
// 256.331 us; speedup vs baseline: 1.3296x; 1.3296x over previous
//
#include <hip/hip_runtime.h>

#define DEVINL __device__ __forceinline__

typedef unsigned short u16;
typedef __attribute__((ext_vector_type(8))) short s16x8;
typedef __attribute__((ext_vector_type(4))) float f32x4;

static constexpr int Bb = 4, Tt = 2048, Cc = 1024, Hh = 16, Dd = 64;
static constexpr int Mm = Bb * Tt;  // 8192
static constexpr int KK = Cc;       // 1024

DEVINL float bf2f(u16 u) { return __uint_as_float(((unsigned)u) << 16); }
DEVINL u16 f2bf(float f) {
  unsigned b = __float_as_uint(f);
  b += 0x7fff + ((b >> 16) & 1);  // RNE
  return (u16)(b >> 16);
}

// ---------------- f32 -> bf16 convert (x4 vectorized) ----------------
__global__ void cvt_bf16(const float* __restrict__ src, u16* __restrict__ dst, int n4) {
  int i = blockIdx.x * blockDim.x + threadIdx.x;
  int st = gridDim.x * blockDim.x;
  for (int g = i; g < n4; g += st) {
    float4 v = ((const float4*)src)[g];
    uint2 o;
    o.x = (unsigned)f2bf(v.x) | ((unsigned)f2bf(v.y) << 16);
    o.y = (unsigned)f2bf(v.z) | ((unsigned)f2bf(v.w) << 16);
    ((uint2*)dst)[g] = o;
  }
}

// ---------------- RoPE in-place on q,k (bf16, (B,H,T,D)) ----------------
__global__ void rope_kernel(u16* __restrict__ q, u16* __restrict__ k,
                            const float* __restrict__ cache) {
  const int total = Bb * Hh * Tt * 8;  // groups of 8 elems
  int i = blockIdx.x * blockDim.x + threadIdx.x;
  int st = gridDim.x * blockDim.x;
  for (int g = i; g < total; g += st) {
    int off = g * 8;
    int t = (off >> 6) & (Tt - 1);
    int d0 = off & 63;
    const float* cp = cache + t * 64 + d0;  // (T, 32, 2) interleaved cos/sin
    float4 c0 = *(const float4*)cp;
    float4 c1 = *(const float4*)(cp + 4);
    float cs[8] = {c0.x, c0.y, c0.z, c0.w, c1.x, c1.y, c1.z, c1.w};
    s16x8 qv = *(s16x8*)(q + off);
    s16x8 kv = *(s16x8*)(k + off);
    s16x8 qo, ko;
#pragma unroll
    for (int p = 0; p < 4; ++p) {
      float c = cs[2 * p], s = cs[2 * p + 1];
      float a = bf2f((u16)qv[2 * p]), b = bf2f((u16)qv[2 * p + 1]);
      qo[2 * p] = (short)f2bf(a * c - b * s);
      qo[2 * p + 1] = (short)f2bf(a * s + b * c);
      a = bf2f((u16)kv[2 * p]); b = bf2f((u16)kv[2 * p + 1]);
      ko[2 * p] = (short)f2bf(a * c - b * s);
      ko[2 * p + 1] = (short)f2bf(a * s + b * c);
    }
    *(s16x8*)(q + off) = qo;
    *(s16x8*)(k + off) = ko;
  }
}

// ---------------- bf16 GEMM: out = A(8192x1024) @ W^T + bias ----------------
// MODE 0: write bf16 into (B,H,T,D) layout, z selects {q,k,v}
// MODE 1: write f32 flat (M x C)
struct GemmArgs {
  const u16* A;
  const u16* W[3];
  const float* bias[3];
  void* out[3];
};

template <int MODE>
__global__ __launch_bounds__(256) void gemm_bt(GemmArgs args) {
  __shared__ __align__(16) u16 As[128 * 64];
  __shared__ __align__(16) u16 Bs[128 * 64];
  const int z = blockIdx.z;
  const u16* __restrict__ A = args.A;
  const u16* __restrict__ Wt = args.W[z];
  const float* __restrict__ bias = args.bias[z];
  const int tid = threadIdx.x, w = tid >> 6, l = tid & 63;
  const int lr = l & 15, lg = l >> 4;
  const int m0 = blockIdx.x * 128, n0 = blockIdx.y * 128;
  const int wr = w >> 1, wc = w & 1;
  f32x4 zero = {0.f, 0.f, 0.f, 0.f};
  f32x4 acc[4][4];
#pragma unroll
  for (int i = 0; i < 4; ++i)
#pragma unroll
    for (int j = 0; j < 4; ++j) acc[i][j] = zero;

  const int srow = l >> 3;        // 0..7
  const int scol = (l & 7) * 8;   // 0..56
  s16x8 av[4], bv[4];
  auto loadAB = [&](int k0) {
#pragma unroll
    for (int i = 0; i < 4; ++i) {
      int row = i * 32 + w * 8 + srow;
      av[i] = *(const s16x8*)(A + (size_t)(m0 + row) * KK + k0 + scol);
      bv[i] = *(const s16x8*)(Wt + (size_t)(n0 + row) * KK + k0 + scol);
    }
  };
  loadAB(0);
  for (int k0 = 0; k0 < KK; k0 += 64) {
    __syncthreads();  // prior compute done reading LDS
#pragma unroll
    for (int i = 0; i < 4; ++i) {
      int row = i * 32 + w * 8 + srow;
      int sc = scol ^ ((row & 7) << 3);  // XOR swizzle, both-sides
      *(s16x8*)&As[row * 64 + sc] = av[i];
      *(s16x8*)&Bs[row * 64 + sc] = bv[i];
    }
    __syncthreads();
    if (k0 + 64 < KK) loadAB(k0 + 64);  // prefetch next tile under MFMA
#pragma unroll
    for (int kk = 0; kk < 2; ++kk) {
      s16x8 af[4], bfr[4];
#pragma unroll
      for (int i = 0; i < 4; ++i)
        af[i] = *(const s16x8*)&As[(wr * 64 + i * 16 + lr) * 64 +
                                   ((kk * 32 + lg * 8) ^ ((lr & 7) << 3))];
#pragma unroll
      for (int j = 0; j < 4; ++j)
        bfr[j] = *(const s16x8*)&Bs[(wc * 64 + j * 16 + lr) * 64 +
                                    ((kk * 32 + lg * 8) ^ ((lr & 7) << 3))];
#pragma unroll
      for (int i = 0; i < 4; ++i)
#pragma unroll
        for (int j = 0; j < 4; ++j)
          acc[i][j] = __builtin_amdgcn_mfma_f32_16x16x32_bf16(af[i], bfr[j], acc[i][j], 0, 0, 0);
    }
  }
  // epilogue: C/D layout col=lane&15, row=(lane>>4)*4+r
  if (MODE == 0) {
    u16* O = (u16*)args.out[z];
#pragma unroll
    for (int j = 0; j < 4; ++j) {
      int ncol = n0 + wc * 64 + j * 16 + lr;
      float bj = bias[ncol];
      int hh = ncol >> 6, dd = ncol & 63;
#pragma unroll
      for (int i = 0; i < 4; ++i) {
#pragma unroll
        for (int r = 0; r < 4; ++r) {
          int mrow = m0 + wr * 64 + i * 16 + lg * 4 + r;
          int bb2 = mrow >> 11, tt2 = mrow & (Tt - 1);
          O[(((size_t)bb2 * Hh + hh) * Tt + tt2) * Dd + dd] = f2bf(acc[i][j][r] + bj);
        }
      }
    }
  } else {
    float* O = (float*)args.out[0];
#pragma unroll
    for (int j = 0; j < 4; ++j) {
      int ncol = n0 + wc * 64 + j * 16 + lr;
      float bj = bias[ncol];
#pragma unroll
      for (int i = 0; i < 4; ++i) {
#pragma unroll
        for (int r = 0; r < 4; ++r) {
          int mrow = m0 + wr * 64 + i * 16 + lg * 4 + r;
          O[(size_t)mrow * Cc + ncol] = acc[i][j][r] + bj;
        }
      }
    }
  }
}

// ---------------- causal flash attention (load-balanced pairing) ----------------
// grid (T/128, B*H), 256 threads; block handles q-tiles {x, 31-x} -> 33 k-tiles each.
__global__ __launch_bounds__(256) void attn_kernel(const u16* __restrict__ Q,
                                                   const u16* __restrict__ K,
                                                   const u16* __restrict__ V,
                                                   u16* __restrict__ Out) {
  __shared__ __align__(16) u16 Ks[64 * 64];        // [key][d] swizzled
  __shared__ __align__(16) u16 VTs[64 * 64];       // [d][key] swizzled
  __shared__ __align__(16) u16 Ps[4 * 16 * 64];    // per-wave [q][key] swizzled
  const int tid = threadIdx.x, w = tid >> 6, l = tid & 63;
  const int lr = l & 15, lg = l >> 4;
  const int bh = blockIdx.y;
  const size_t base = (size_t)bh * Tt * Dd;
  const u16* Qp = Q + base;
  const u16* Kp = K + base;
  const u16* Vp = V + base;
  const int bb2 = bh >> 4, hh = bh & 15;
  f32x4 zero = {0.f, 0.f, 0.f, 0.f};

  auto process = [&](int qt) {
    const int qb0 = qt * 64;
    const int qrow = qb0 + w * 16 + lr;
    s16x8 qf[2];
    qf[0] = *(const s16x8*)(Qp + (size_t)qrow * 64 + lg * 8);
    qf[1] = *(const s16x8*)(Qp + (size_t)qrow * 64 + 32 + lg * 8);
    f32x4 o[4] = {zero, zero, zero, zero};
    float mrow[4] = {-1e30f, -1e30f, -1e30f, -1e30f};
    float lsum[4] = {0.f, 0.f, 0.f, 0.f};
    const int ktiles = qt + 1;
    s16x8 kv[2], vv[2];
    auto loadKV = [&](int kk0) {
#pragma unroll
      for (int i = 0; i < 2; ++i) {
        int d0 = (w + i * 4) * 8;
        kv[i] = *(const s16x8*)(Kp + (size_t)(kk0 + l) * 64 + d0);
        vv[i] = *(const s16x8*)(Vp + (size_t)(kk0 + l) * 64 + d0);
      }
    };
    loadKV(0);
    for (int kt = 0; kt < ktiles; ++kt) {
      const int kk0 = kt * 64;
      __syncthreads();  // prior iter done reading Ks/VTs
#pragma unroll
      for (int i = 0; i < 2; ++i) {
        int d0 = (w + i * 4) * 8;
        *(s16x8*)&Ks[l * 64 + (d0 ^ ((l & 7) << 3))] = kv[i];
#pragma unroll
        for (int j = 0; j < 8; ++j)
          VTs[(d0 + j) * 64 + (l ^ (j << 3))] = (u16)vv[i][j];  // (d0+j)&7 == j
      }
      __syncthreads();
      if (kt + 1 < ktiles) loadKV(kk0 + 64);  // prefetch under compute
      // ---- QK^T: S[16q x 64key] in 4 col-frags
      float pv[4][4];
#pragma unroll
      for (int cf = 0; cf < 4; ++cf) {
        f32x4 s = zero;
#pragma unroll
        for (int kf = 0; kf < 2; ++kf) {
          s16x8 kb = *(const s16x8*)&Ks[(cf * 16 + lr) * 64 +
                                        ((kf * 32 + lg * 8) ^ ((lr & 7) << 3))];
          s = __builtin_amdgcn_mfma_f32_16x16x32_bf16(qf[kf], kb, s, 0, 0, 0);
        }
        if (kt == ktiles - 1) {  // diagonal tile: causal mask (wave-uniform branch)
          int key = kk0 + cf * 16 + lr;
#pragma unroll
          for (int r = 0; r < 4; ++r) {
            int qg = qb0 + w * 16 + lg * 4 + r;
            pv[cf][r] = (key <= qg) ? s[r] * 0.125f : -1e10f;
          }
        } else {  // interior tile: fully unmasked
#pragma unroll
          for (int r = 0; r < 4; ++r) pv[cf][r] = s[r] * 0.125f;
        }
      }
      // ---- online softmax (rows live across the 16-lane groups)
#pragma unroll
      for (int r = 0; r < 4; ++r) {
        float tm = fmaxf(fmaxf(pv[0][r], pv[1][r]), fmaxf(pv[2][r], pv[3][r]));
#pragma unroll
        for (int off = 8; off > 0; off >>= 1) tm = fmaxf(tm, __shfl_xor(tm, off, 16));
        float mnew = fmaxf(mrow[r], tm);
        float fsc = __expf(mrow[r] - mnew);
        float psum = 0.f;
#pragma unroll
        for (int cf = 0; cf < 4; ++cf) {
          float p = __expf(pv[cf][r] - mnew);
          pv[cf][r] = p;
          psum += p;
        }
#pragma unroll
        for (int off = 8; off > 0; off >>= 1) psum += __shfl_xor(psum, off, 16);
        lsum[r] = lsum[r] * fsc + psum;
        mrow[r] = mnew;
        o[0][r] *= fsc; o[1][r] *= fsc; o[2][r] *= fsc; o[3][r] *= fsc;
      }
      // ---- P -> per-wave LDS (C-frag layout -> A-frag layout)
#pragma unroll
      for (int cf = 0; cf < 4; ++cf) {
#pragma unroll
        for (int r = 0; r < 4; ++r) {
          int row = lg * 4 + r;
          Ps[w * 1024 + row * 64 + ((cf * 16 + lr) ^ ((row & 7) << 3))] = f2bf(pv[cf][r]);
        }
      }
      // ---- PV: O += P(16x64) @ V(64x64)
#pragma unroll
      for (int kk = 0; kk < 2; ++kk) {
        s16x8 pa = *(const s16x8*)&Ps[w * 1024 + lr * 64 +
                                      ((kk * 32 + lg * 8) ^ ((lr & 7) << 3))];
#pragma unroll
        for (int jf = 0; jf < 4; ++jf) {
          s16x8 vb = *(const s16x8*)&VTs[(jf * 16 + lr) * 64 +
                                         ((kk * 32 + lg * 8) ^ ((lr & 7) << 3))];
          o[jf] = __builtin_amdgcn_mfma_f32_16x16x32_bf16(pa, vb, o[jf], 0, 0, 0);
        }
      }
    }
    // ---- epilogue: write (B,T,H*D) bf16
#pragma unroll
    for (int jf = 0; jf < 4; ++jf) {
#pragma unroll
      for (int r = 0; r < 4; ++r) {
        int tq = qb0 + w * 16 + lg * 4 + r;
        float val = o[jf][r] / lsum[r];
        Out[((size_t)(bb2 * Tt + tq)) * Cc + hh * 64 + jf * 16 + lr] = f2bf(val);
      }
    }
  };

  process(blockIdx.x);                   // light q-tile: x+1 k-tiles
  process((Tt / 64 - 1) - blockIdx.x);   // heavy q-tile: 32-x k-tiles (total 33, balanced)
}

extern "C" void kernel_launch(void* const* d_in, const int* in_sizes, int n_in,
                              void* d_out, int out_size, void* d_ws, size_t ws_size,
                              hipStream_t stream) {
  (void)in_sizes; (void)n_in; (void)out_size; (void)ws_size;
  const float* x = (const float*)d_in[0];
  const float* Wq = (const float*)d_in[1];
  const float* bq = (const float*)d_in[2];
  const float* Wk = (const float*)d_in[3];
  const float* bk = (const float*)d_in[4];
  const float* Wv = (const float*)d_in[5];
  const float* bv = (const float*)d_in[6];
  const float* Wp = (const float*)d_in[7];
  const float* bp = (const float*)d_in[8];
  const float* rope = (const float*)d_in[9];

  char* ws = (char*)d_ws;
  const size_t MB = 1024 * 1024;
  u16* xb  = (u16*)(ws + 0);        // 16 MB: x as bf16 (8192x1024)
  u16* wqb = (u16*)(ws + 16 * MB);  // 2 MB each
  u16* wkb = (u16*)(ws + 18 * MB);
  u16* wvb = (u16*)(ws + 20 * MB);
  u16* wpb = (u16*)(ws + 22 * MB);
  u16* qb  = (u16*)(ws + 24 * MB);  // 16 MB each, (B,H,T,D) bf16
  u16* kb  = (u16*)(ws + 40 * MB);
  u16* vb  = (u16*)(ws + 56 * MB);
  u16* att = (u16*)(ws + 72 * MB);  // 16 MB, (B,T,C) bf16  -> ends 88 MB

  cvt_bf16<<<2048, 256, 0, stream>>>(x, xb, (Mm * Cc) / 4);
  cvt_bf16<<<512, 256, 0, stream>>>(Wq, wqb, (Cc * Cc) / 4);
  cvt_bf16<<<512, 256, 0, stream>>>(Wk, wkb, (Cc * Cc) / 4);
  cvt_bf16<<<512, 256, 0, stream>>>(Wv, wvb, (Cc * Cc) / 4);
  cvt_bf16<<<512, 256, 0, stream>>>(Wp, wpb, (Cc * Cc) / 4);

  GemmArgs ga;
  ga.A = xb;
  ga.W[0] = wqb; ga.W[1] = wkb; ga.W[2] = wvb;
  ga.bias[0] = bq; ga.bias[1] = bk; ga.bias[2] = bv;
  ga.out[0] = qb; ga.out[1] = kb; ga.out[2] = vb;
  gemm_bt<0><<<dim3(Mm / 128, Cc / 128, 3), 256, 0, stream>>>(ga);

  rope_kernel<<<2048, 256, 0, stream>>>(qb, kb, rope);

  attn_kernel<<<dim3(Tt / 128, Bb * Hh), 256, 0, stream>>>(qb, kb, vb, att);

  GemmArgs gp;
  gp.A = att;
  gp.W[0] = wpb; gp.W[1] = wpb; gp.W[2] = wpb;
  gp.bias[0] = bp; gp.bias[1] = bp; gp.bias[2] = bp;
  gp.out[0] = d_out; gp.out[1] = d_out; gp.out[2] = d_out;
  gemm_bt<1><<<dim3(Mm / 128, Cc / 128, 1), 256, 0, stream>>>(gp);
}

// Round 3
// 227.106 us; speedup vs baseline: 1.5007x; 1.1287x over previous
//
#include <hip/hip_runtime.h>

#define DEVINL __device__ __forceinline__

typedef unsigned short u16;
typedef __attribute__((ext_vector_type(8))) short s16x8;
typedef __attribute__((ext_vector_type(4))) float f32x4;

static constexpr int Bb = 4, Tt = 2048, Cc = 1024, Hh = 16, Dd = 64;
static constexpr int Mm = Bb * Tt;  // 8192
static constexpr int KK = Cc;       // 1024

DEVINL float bf2f(u16 u) { return __uint_as_float(((unsigned)u) << 16); }
DEVINL u16 f2bf(float f) {
  unsigned b = __float_as_uint(f);
  b += 0x7fff + ((b >> 16) & 1);  // RNE
  return (u16)(b >> 16);
}

#define GLDS(gsrc, ldst) \
  __builtin_amdgcn_global_load_lds((const __attribute__((address_space(1))) void*)(gsrc), \
                                   (__attribute__((address_space(3))) void*)(ldst), 16, 0, 0)

// ---------------- f32 -> bf16 convert (x4 vectorized) ----------------
__global__ void cvt_bf16(const float* __restrict__ src, u16* __restrict__ dst, int n4) {
  int i = blockIdx.x * blockDim.x + threadIdx.x;
  int st = gridDim.x * blockDim.x;
  for (int g = i; g < n4; g += st) {
    float4 v = ((const float4*)src)[g];
    uint2 o;
    o.x = (unsigned)f2bf(v.x) | ((unsigned)f2bf(v.y) << 16);
    o.y = (unsigned)f2bf(v.z) | ((unsigned)f2bf(v.w) << 16);
    ((uint2*)dst)[g] = o;
  }
}

// ---------------- 4 weight converts in one launch ----------------
struct Cvt4Args { const float* s[4]; u16* d[4]; };
__global__ void cvt4(Cvt4Args a, int n4) {
  const float* __restrict__ src = a.s[blockIdx.y];
  u16* __restrict__ dst = a.d[blockIdx.y];
  int i = blockIdx.x * blockDim.x + threadIdx.x;
  int st = gridDim.x * blockDim.x;
  for (int g = i; g < n4; g += st) {
    float4 v = ((const float4*)src)[g];
    uint2 o;
    o.x = (unsigned)f2bf(v.x) | ((unsigned)f2bf(v.y) << 16);
    o.y = (unsigned)f2bf(v.z) | ((unsigned)f2bf(v.w) << 16);
    ((uint2*)dst)[g] = o;
  }
}

// ---------------- RoPE in-place on q,k (bf16, (B,H,T,D)) ----------------
__global__ void rope_kernel(u16* __restrict__ q, u16* __restrict__ k,
                            const float* __restrict__ cache) {
  const int total = Bb * Hh * Tt * 8;  // groups of 8 elems
  int i = blockIdx.x * blockDim.x + threadIdx.x;
  int st = gridDim.x * blockDim.x;
  for (int g = i; g < total; g += st) {
    int off = g * 8;
    int t = (off >> 6) & (Tt - 1);
    int d0 = off & 63;
    const float* cp = cache + t * 64 + d0;  // (T, 32, 2) interleaved cos/sin
    float4 c0 = *(const float4*)cp;
    float4 c1 = *(const float4*)(cp + 4);
    float cs[8] = {c0.x, c0.y, c0.z, c0.w, c1.x, c1.y, c1.z, c1.w};
    s16x8 qv = *(s16x8*)(q + off);
    s16x8 kv = *(s16x8*)(k + off);
    s16x8 qo, ko;
#pragma unroll
    for (int p = 0; p < 4; ++p) {
      float c = cs[2 * p], s = cs[2 * p + 1];
      float a = bf2f((u16)qv[2 * p]), b = bf2f((u16)qv[2 * p + 1]);
      qo[2 * p] = (short)f2bf(a * c - b * s);
      qo[2 * p + 1] = (short)f2bf(a * s + b * c);
      a = bf2f((u16)kv[2 * p]); b = bf2f((u16)kv[2 * p + 1]);
      ko[2 * p] = (short)f2bf(a * c - b * s);
      ko[2 * p + 1] = (short)f2bf(a * s + b * c);
    }
    *(s16x8*)(q + off) = qo;
    *(s16x8*)(k + off) = ko;
  }
}

// ---------------- V (B,H,T,D) -> VT (B,H,D,T) ----------------
__global__ void vtrans(const u16* __restrict__ V, u16* __restrict__ VT) {
  __shared__ u16 lds[64 * 65];
  const int bh = blockIdx.y, t0 = blockIdx.x * 64;
  const int tid = threadIdx.x;
  const u16* src = V + (size_t)bh * Tt * Dd;
  u16* dst = VT + (size_t)bh * Tt * Dd;
  const int tt = tid >> 3, c8 = tid & 7;
#pragma unroll
  for (int it = 0; it < 2; ++it) {
    int t = it * 32 + tt;
    s16x8 v = *(const s16x8*)(src + (size_t)(t0 + t) * 64 + c8 * 8);
#pragma unroll
    for (int j = 0; j < 8; ++j) lds[(c8 * 8 + j) * 65 + t] = (u16)v[j];
  }
  __syncthreads();
#pragma unroll
  for (int it = 0; it < 2; ++it) {
    int id = it * 256 + tid, d = id >> 3, c = id & 7;
    s16x8 v;
#pragma unroll
    for (int j = 0; j < 8; ++j) v[j] = (short)lds[d * 65 + c * 8 + j];
    *(s16x8*)(dst + (size_t)d * Tt + t0 + c * 8) = v;
  }
}

// ---------------- bf16 GEMM: out = A(8192x1024) @ W^T + bias ----------------
// m97 structure: global_load_lds staging, pre-swizzled source, 2-barrier loop.
struct GemmArgs {
  const u16* A;
  const u16* W[3];
  const float* bias[3];
  void* out[3];
};

template <int MODE>
__global__ __launch_bounds__(256) void gemm_bt(GemmArgs args) {
  __shared__ __align__(16) u16 As[128 * 64];
  __shared__ __align__(16) u16 Bs[128 * 64];
  const int z = blockIdx.z;
  const u16* __restrict__ A = args.A;
  const u16* __restrict__ Wt = args.W[z];
  const float* __restrict__ bias = args.bias[z];
  const int tid = threadIdx.x, w = tid >> 6, l = tid & 63;
  const int lr = l & 15, lg = l >> 4;
  const int m0 = blockIdx.x * 128, n0 = blockIdx.y * 128;
  const int wr = w >> 1, wc = w & 1;
  f32x4 zero = {0.f, 0.f, 0.f, 0.f};
  f32x4 acc[4][4];
#pragma unroll
  for (int i = 0; i < 4; ++i)
#pragma unroll
    for (int j = 0; j < 4; ++j) acc[i][j] = zero;

  // glds staging: LDS slot (row, c8) <- global col8 (c8 ^ (row&7)); row&7 == l>>3
  const int srow = l >> 3;                     // 0..7
  const int scolsw = ((l & 7) ^ (l >> 3)) * 8; // pre-swizzled source col (elems)

  for (int k0 = 0; k0 < KK; k0 += 64) {
#pragma unroll
    for (int i = 0; i < 4; ++i) {
      int row = i * 32 + w * 8 + srow;
      GLDS(A + (size_t)(m0 + row) * KK + k0 + scolsw, &As[(i * 32 + w * 8) * 64]);
      GLDS(Wt + (size_t)(n0 + row) * KK + k0 + scolsw, &Bs[(i * 32 + w * 8) * 64]);
    }
    __syncthreads();  // drains vmcnt -> tiles ready
#pragma unroll
    for (int kk = 0; kk < 2; ++kk) {
      s16x8 af[4], bfr[4];
#pragma unroll
      for (int i = 0; i < 4; ++i)
        af[i] = *(const s16x8*)&As[(wr * 64 + i * 16 + lr) * 64 +
                                   ((kk * 32 + lg * 8) ^ ((lr & 7) << 3))];
#pragma unroll
      for (int j = 0; j < 4; ++j)
        bfr[j] = *(const s16x8*)&Bs[(wc * 64 + j * 16 + lr) * 64 +
                                    ((kk * 32 + lg * 8) ^ ((lr & 7) << 3))];
#pragma unroll
      for (int i = 0; i < 4; ++i)
#pragma unroll
        for (int j = 0; j < 4; ++j)
          acc[i][j] = __builtin_amdgcn_mfma_f32_16x16x32_bf16(af[i], bfr[j], acc[i][j], 0, 0, 0);
    }
    __syncthreads();  // all reads done before next stage overwrites
  }
  // epilogue: C/D layout col=lane&15, row=(lane>>4)*4+r
  if (MODE == 0) {
    u16* O = (u16*)args.out[z];
#pragma unroll
    for (int j = 0; j < 4; ++j) {
      int ncol = n0 + wc * 64 + j * 16 + lr;
      float bj = bias[ncol];
      int hh = ncol >> 6, dd = ncol & 63;
#pragma unroll
      for (int i = 0; i < 4; ++i) {
#pragma unroll
        for (int r = 0; r < 4; ++r) {
          int mrow = m0 + wr * 64 + i * 16 + lg * 4 + r;
          int bb2 = mrow >> 11, tt2 = mrow & (Tt - 1);
          O[(((size_t)bb2 * Hh + hh) * Tt + tt2) * Dd + dd] = f2bf(acc[i][j][r] + bj);
        }
      }
    }
  } else {
    float* O = (float*)args.out[0];
#pragma unroll
    for (int j = 0; j < 4; ++j) {
      int ncol = n0 + wc * 64 + j * 16 + lr;
      float bj = bias[ncol];
#pragma unroll
      for (int i = 0; i < 4; ++i) {
#pragma unroll
        for (int r = 0; r < 4; ++r) {
          int mrow = m0 + wr * 64 + i * 16 + lg * 4 + r;
          O[(size_t)mrow * Cc + ncol] = acc[i][j][r] + bj;
        }
      }
    }
  }
}

// ---------------- causal flash attention ----------------
// KVBLK=128, glds staging of K and VT, log2-domain softmax with defer-max.
// grid (16, B*H), 256 threads; block handles q-tiles {x, 31-x} -> 17 k128-tiles.
__global__ __launch_bounds__(256, 4) void attn_kernel(const u16* __restrict__ Q,
                                                      const u16* __restrict__ K,
                                                      const u16* __restrict__ VTg,
                                                      u16* __restrict__ Out) {
  __shared__ __align__(16) u16 Ks[128 * 64];   // [key][d] swizzled c8^=(key&7)
  __shared__ __align__(16) u16 VTs[64 * 128];  // [d][key] swizzled c8^=(d&7)
  __shared__ __align__(16) u16 Ps[4 * 16 * 32];  // per-wave [q][32key chunk] swizzled
  const int tid = threadIdx.x, w = tid >> 6, l = tid & 63;
  const int lr = l & 15, lg = l >> 4;
  const int bh = blockIdx.y;
  const size_t base = (size_t)bh * Tt * Dd;
  const u16* Qp = Q + base;
  const u16* Kp = K + base;
  const u16* Vp = VTg + base;  // (D, T) per bh
  const int bb2 = bh >> 4, hh = bh & 15;
  const float CS = 0.18033688f;  // 0.125 * log2(e); softmax in log2 domain
  const float NEG = -3.0e9f;
  f32x4 zero = {0.f, 0.f, 0.f, 0.f};
  // glds lane constants
  const int krow_l = l >> 3, kc8sw = ((l & 7) ^ (l >> 3)) * 8;  // K stage
  const int vrow_l = l >> 4, vc8 = l & 15;                      // VT stage

  auto process = [&](int qt) {
    const int qb0 = qt * 64;
    const int qrow = qb0 + w * 16 + lr;
    s16x8 qf[2];
    qf[0] = *(const s16x8*)(Qp + (size_t)qrow * 64 + lg * 8);
    qf[1] = *(const s16x8*)(Qp + (size_t)qrow * 64 + 32 + lg * 8);
    f32x4 o[4] = {zero, zero, zero, zero};
    float m[4] = {-3e38f, -3e38f, -3e38f, -3e38f};
    float lsum[4] = {0.f, 0.f, 0.f, 0.f};
    const int ktiles = (qt + 2) >> 1;
    for (int kt = 0; kt < ktiles; ++kt) {
      const int kk0 = kt * 128;
      // ---- stage K[128][64] and VT[64][128] via global_load_lds
#pragma unroll
      for (int i = 0; i < 4; ++i) {
        int krow = i * 32 + w * 8 + krow_l;
        GLDS(Kp + (size_t)(kk0 + krow) * 64 + kc8sw, &Ks[(i * 32 + w * 8) * 64]);
        int d = i * 16 + w * 4 + vrow_l;
        GLDS(Vp + (size_t)d * Tt + kk0 + ((vc8 ^ (d & 7)) * 8), &VTs[(i * 16 + w * 4) * 128]);
      }
      __syncthreads();
      // ---- QK^T: S[16q x 128key] in 8 col-frags
      float pv[8][4];
      const int diag = (kt == ktiles - 1);
      __builtin_amdgcn_s_setprio(1);
#pragma unroll
      for (int cf = 0; cf < 8; ++cf) {
        f32x4 s = zero;
#pragma unroll
        for (int kf = 0; kf < 2; ++kf) {
          s16x8 kb = *(const s16x8*)&Ks[(cf * 16 + lr) * 64 + (((kf * 4 + lg) ^ (lr & 7)) << 3)];
          s = __builtin_amdgcn_mfma_f32_16x16x32_bf16(qf[kf], kb, s, 0, 0, 0);
        }
        if (diag) {
          int key = kk0 + cf * 16 + lr;
#pragma unroll
          for (int r = 0; r < 4; ++r) {
            int qg = qb0 + w * 16 + lg * 4 + r;
            pv[cf][r] = (key <= qg) ? s[r] * CS : NEG;
          }
        } else {
#pragma unroll
          for (int r = 0; r < 4; ++r) pv[cf][r] = s[r] * CS;
        }
      }
      __builtin_amdgcn_s_setprio(0);
      // ---- online softmax (log2 domain, defer-max T13)
      float tm[4];
#pragma unroll
      for (int r = 0; r < 4; ++r) {
        float t0 = fmaxf(fmaxf(pv[0][r], pv[1][r]), fmaxf(pv[2][r], pv[3][r]));
        float t1 = fmaxf(fmaxf(pv[4][r], pv[5][r]), fmaxf(pv[6][r], pv[7][r]));
        float t = fmaxf(t0, t1);
#pragma unroll
        for (int off = 8; off > 0; off >>= 1) t = fmaxf(t, __shfl_xor(t, off, 16));
        tm[r] = t;
      }
      int stable = (tm[0] <= m[0] + 11.5f) && (tm[1] <= m[1] + 11.5f) &&
                   (tm[2] <= m[2] + 11.5f) && (tm[3] <= m[3] + 11.5f);
      if (!__all(stable)) {
#pragma unroll
        for (int r = 0; r < 4; ++r) {
          float mn = fmaxf(m[r], tm[r]);
          float fsc = exp2f(m[r] - mn);
          lsum[r] *= fsc;
          o[0][r] *= fsc; o[1][r] *= fsc; o[2][r] *= fsc; o[3][r] *= fsc;
          m[r] = mn;
        }
      }
      float psum[4] = {0.f, 0.f, 0.f, 0.f};
#pragma unroll
      for (int cf = 0; cf < 8; ++cf)
#pragma unroll
        for (int r = 0; r < 4; ++r) {
          float p = exp2f(pv[cf][r] - m[r]);
          pv[cf][r] = p;
          psum[r] += p;
        }
#pragma unroll
      for (int r = 0; r < 4; ++r) {
        float ps = psum[r];
#pragma unroll
        for (int off = 8; off > 0; off >>= 1) ps += __shfl_xor(ps, off, 16);
        lsum[r] += ps;
      }
      // ---- PV in 4 chunks of 32 keys: P->LDS (b-elem, swizzled c8^=(row>>2)), read A-frag, mfma
#pragma unroll
      for (int kk = 0; kk < 4; ++kk) {
#pragma unroll
        for (int c = 0; c < 2; ++c) {
          int cf = kk * 2 + c;
          int c8w = c * 2 + (lr >> 3);
#pragma unroll
          for (int r = 0; r < 4; ++r) {
            int row = lg * 4 + r;
            Ps[w * 512 + row * 32 + ((c8w ^ (row >> 2)) << 3) + (lr & 7)] = f2bf(pv[cf][r]);
          }
        }
        s16x8 pa = *(const s16x8*)&Ps[w * 512 + lr * 32 + ((lg ^ (lr >> 2)) << 3)];
        __builtin_amdgcn_s_setprio(1);
#pragma unroll
        for (int jf = 0; jf < 4; ++jf) {
          s16x8 vb = *(const s16x8*)&VTs[(jf * 16 + lr) * 128 + (((kk * 4 + lg) ^ (lr & 7)) << 3)];
          o[jf] = __builtin_amdgcn_mfma_f32_16x16x32_bf16(pa, vb, o[jf], 0, 0, 0);
        }
        __builtin_amdgcn_s_setprio(0);
      }
      __syncthreads();  // all reads done before next stage overwrites
    }
    // ---- epilogue: write (B,T,H*D) bf16
#pragma unroll
    for (int jf = 0; jf < 4; ++jf) {
#pragma unroll
      for (int r = 0; r < 4; ++r) {
        int tq = qb0 + w * 16 + lg * 4 + r;
        float val = o[jf][r] / lsum[r];
        Out[((size_t)(bb2 * Tt + tq)) * Cc + hh * 64 + jf * 16 + lr] = f2bf(val);
      }
    }
  };

  process(blockIdx.x);        // light q-tile
  process(31 - blockIdx.x);   // heavy q-tile (total 17 k-tiles, balanced)
}

extern "C" void kernel_launch(void* const* d_in, const int* in_sizes, int n_in,
                              void* d_out, int out_size, void* d_ws, size_t ws_size,
                              hipStream_t stream) {
  (void)in_sizes; (void)n_in; (void)out_size; (void)ws_size;
  const float* x = (const float*)d_in[0];
  const float* Wq = (const float*)d_in[1];
  const float* bq = (const float*)d_in[2];
  const float* Wk = (const float*)d_in[3];
  const float* bk = (const float*)d_in[4];
  const float* Wv = (const float*)d_in[5];
  const float* bv = (const float*)d_in[6];
  const float* Wp = (const float*)d_in[7];
  const float* bp = (const float*)d_in[8];
  const float* rope = (const float*)d_in[9];

  char* ws = (char*)d_ws;
  const size_t MB = 1024 * 1024;
  u16* xb  = (u16*)(ws + 0);        // 16 MB: x as bf16; dead after QKV gemm
  u16* vt  = (u16*)(ws + 0);        // 16 MB: VT (B,H,D,T), written after gemm (reuses xb)
  u16* wqb = (u16*)(ws + 16 * MB);  // 2 MB each
  u16* wkb = (u16*)(ws + 18 * MB);
  u16* wvb = (u16*)(ws + 20 * MB);
  u16* wpb = (u16*)(ws + 22 * MB);
  u16* qb  = (u16*)(ws + 24 * MB);  // 16 MB each, (B,H,T,D) bf16
  u16* kb  = (u16*)(ws + 40 * MB);
  u16* vb  = (u16*)(ws + 56 * MB);
  u16* att = (u16*)(ws + 72 * MB);  // 16 MB, (B,T,C) bf16 -> ends 88 MB

  cvt_bf16<<<2048, 256, 0, stream>>>(x, xb, (Mm * Cc) / 4);
  Cvt4Args ca;
  ca.s[0] = Wq; ca.s[1] = Wk; ca.s[2] = Wv; ca.s[3] = Wp;
  ca.d[0] = wqb; ca.d[1] = wkb; ca.d[2] = wvb; ca.d[3] = wpb;
  cvt4<<<dim3(256, 4), 256, 0, stream>>>(ca, (Cc * Cc) / 4);

  GemmArgs ga;
  ga.A = xb;
  ga.W[0] = wqb; ga.W[1] = wkb; ga.W[2] = wvb;
  ga.bias[0] = bq; ga.bias[1] = bk; ga.bias[2] = bv;
  ga.out[0] = qb; ga.out[1] = kb; ga.out[2] = vb;
  gemm_bt<0><<<dim3(Mm / 128, Cc / 128, 3), 256, 0, stream>>>(ga);

  rope_kernel<<<2048, 256, 0, stream>>>(qb, kb, rope);
  vtrans<<<dim3(Tt / 64, Bb * Hh), 256, 0, stream>>>(vb, vt);  // overwrites xb (dead)

  attn_kernel<<<dim3(16, Bb * Hh), 256, 0, stream>>>(qb, kb, vt, att);

  GemmArgs gp;
  gp.A = att;
  gp.W[0] = wpb; gp.W[1] = wpb; gp.W[2] = wpb;
  gp.bias[0] = bp; gp.bias[1] = bp; gp.bias[2] = bp;
  gp.out[0] = d_out; gp.out[1] = d_out; gp.out[2] = d_out;
  gemm_bt<1><<<dim3(Mm / 128, Cc / 128, 1), 256, 0, stream>>>(gp);
}